// Round 3
// baseline (7072.325 us; speedup 1.0000x reference)
//
#include <hip/hip_runtime.h>
#include <math.h>

// ---------------------------------------------------------------------------
// DAGNN: h=relu(nf@W1+b1); logits=h@W2+b2; 20x (x<-A x) with fused gated sum
// out = sum_k sigmoid(x_k . Wg + bg) * x_k    (k=0..20, x_0 = logits)
//
// Hop = SpMM with receiver-CSR, SENDER-BLOCKED for L2 locality:
//   key = (sender >> SBITS) * n + receiver; each wave owns 16 receivers
//   (acc[16] in VGPRs) and sweeps sender blocks in phase -> gathers hit a
//   2 MB window resident in each XCD's 4 MB L2.
// ---------------------------------------------------------------------------

#define F_IN 512
#define C 64        // hidden == n_classes == 64
#define SBITS 13    // sender block = 8192 nodes = 2 MB of x
#define KNODES 16   // receivers per wave

// ---------- GEMM1: [M,512] @ [512,64] + b1, relu --------------------------
__global__ __launch_bounds__(256) void gemm1_relu(
    const float* __restrict__ A, const float* __restrict__ W1,
    const float* __restrict__ b1, float* __restrict__ H, int M)
{
  __shared__ __align__(16) float As[16][68];
  __shared__ __align__(16) float Bs[16][64];
  int t = threadIdx.x;
  int tx = t & 15, ty = t >> 4;
  int m0 = blockIdx.x * 64;
  int lm = t >> 2, lk = (t & 3) << 2;
  const float* Arow = A + (size_t)(m0 + lm) * F_IN;
  bool aok = (m0 + lm) < M;
  float acc[4][4] = {};

  for (int k0 = 0; k0 < F_IN; k0 += 16) {
    float4 av = make_float4(0.f, 0.f, 0.f, 0.f);
    if (aok) av = *(const float4*)(Arow + k0 + lk);
    float bv[4];
#pragma unroll
    for (int i = 0; i < 4; ++i)
      bv[i] = W1[(size_t)(k0 + (t >> 6) + (i << 2)) * C + (t & 63)];
    __syncthreads();
    As[lk + 0][lm] = av.x; As[lk + 1][lm] = av.y;
    As[lk + 2][lm] = av.z; As[lk + 3][lm] = av.w;
#pragma unroll
    for (int i = 0; i < 4; ++i)
      Bs[(t >> 6) + (i << 2)][t & 63] = bv[i];
    __syncthreads();
#pragma unroll
    for (int kk = 0; kk < 16; ++kk) {
      float4 a = *(const float4*)&As[kk][ty << 2];
      float4 b = *(const float4*)&Bs[kk][tx << 2];
      acc[0][0] += a.x * b.x; acc[0][1] += a.x * b.y; acc[0][2] += a.x * b.z; acc[0][3] += a.x * b.w;
      acc[1][0] += a.y * b.x; acc[1][1] += a.y * b.y; acc[1][2] += a.y * b.z; acc[1][3] += a.y * b.w;
      acc[2][0] += a.z * b.x; acc[2][1] += a.z * b.y; acc[2][2] += a.z * b.z; acc[2][3] += a.z * b.w;
      acc[3][0] += a.w * b.x; acc[3][1] += a.w * b.y; acc[3][2] += a.w * b.z; acc[3][3] += a.w * b.w;
    }
    __syncthreads();
  }
  float4 bb = *(const float4*)&b1[tx << 2];
#pragma unroll
  for (int i = 0; i < 4; ++i) {
    int row = m0 + (ty << 2) + i;
    if (row < M) {
      float4 r;
      r.x = fmaxf(acc[i][0] + bb.x, 0.f);
      r.y = fmaxf(acc[i][1] + bb.y, 0.f);
      r.z = fmaxf(acc[i][2] + bb.z, 0.f);
      r.w = fmaxf(acc[i][3] + bb.w, 0.f);
      *(float4*)&H[(size_t)row * C + (tx << 2)] = r;
    }
  }
}

// ---------- GEMM2 + gate init ---------------------------------------------
__global__ __launch_bounds__(256) void gemm2_gate(
    const float* __restrict__ h, const float* __restrict__ W2,
    const float* __restrict__ b2, const float* __restrict__ Wg,
    const float* __restrict__ bgp, float* __restrict__ logits,
    float* __restrict__ out, int n)
{
  __shared__ float W2s[C * C];
  int t = threadIdx.x;
  for (int i = t; i < C * C; i += blockDim.x) W2s[i] = W2[i];
  __syncthreads();
  int lane = t & 63, wid = t >> 6;
  int wave = blockIdx.x * (blockDim.x >> 6) + wid;
  int nw = gridDim.x * (blockDim.x >> 6);
  float wg = Wg[lane], bgv = bgp[0], b2v = b2[lane];
  for (int node = wave; node < n; node += nw) {
    float hv = h[(size_t)node * C + lane];
    float acc = b2v;
#pragma unroll
    for (int k = 0; k < C; ++k) {
      float hk = __shfl(hv, k, 64);
      acc += hk * W2s[k * C + lane];
    }
    float p = acc * wg;
#pragma unroll
    for (int off = 32; off > 0; off >>= 1) p += __shfl_xor(p, off, 64);
    float g = 1.f / (1.f + expf(-(p + bgv)));
    size_t o = (size_t)node * C + lane;
    logits[o] = acc;
    out[o] = g * acc;
  }
}

// ---------- CSR build (sender-blocked key) --------------------------------
__global__ void hist_edges(const int* __restrict__ send,
                           const int* __restrict__ recv,
                           int* __restrict__ cnt, int E, int n) {
  int i = blockIdx.x * blockDim.x + threadIdx.x;
  if (i < E) {
    int key = (send[i] >> SBITS) * n + recv[i];
    atomicAdd(&cnt[key], 1);
  }
}

// hierarchical scan, step 1: per-1024-chunk exclusive scan + chunk totals
__global__ __launch_bounds__(1024) void scan1(
    const int* __restrict__ cnt, int* __restrict__ excl_out,
    int* __restrict__ partials, int nbins)
{
  __shared__ int wsum[16];
  int t = threadIdx.x, lane = t & 63, wid = t >> 6;
  int i = blockIdx.x * 1024 + t;
  int v = (i < nbins) ? cnt[i] : 0;
  int incl = v;
#pragma unroll
  for (int off = 1; off < 64; off <<= 1) {
    int u = __shfl_up(incl, off, 64);
    if (lane >= off) incl += u;
  }
  if (lane == 63) wsum[wid] = incl;
  __syncthreads();
  if (t < 16) {
    int ws = wsum[t];
#pragma unroll
    for (int off = 1; off < 16; off <<= 1) {
      int u = __shfl_up(ws, off, 16);
      if ((t & 15) >= off) ws += u;
    }
    wsum[t] = ws;
  }
  __syncthreads();
  int excl = ((wid > 0) ? wsum[wid - 1] : 0) + (incl - v);
  if (i < nbins) excl_out[i] = excl;
  if (t == 1023) partials[blockIdx.x] = excl + v;  // chunk total
}

// step 2: single-block in-place exclusive scan of chunk totals
__global__ __launch_bounds__(1024) void scan2(int* __restrict__ p, int nb)
{
  __shared__ int wsum[16];
  int t = threadIdx.x, lane = t & 63, wid = t >> 6;
  int carry = 0;
  for (int base = 0; base < nb; base += 1024) {
    int idx = base + t;
    int v = (idx < nb) ? p[idx] : 0;
    int incl = v;
#pragma unroll
    for (int off = 1; off < 64; off <<= 1) {
      int u = __shfl_up(incl, off, 64);
      if (lane >= off) incl += u;
    }
    if (lane == 63) wsum[wid] = incl;
    __syncthreads();
    if (t < 16) {
      int ws = wsum[t];
#pragma unroll
      for (int off = 1; off < 16; off <<= 1) {
        int u = __shfl_up(ws, off, 16);
        if ((t & 15) >= off) ws += u;
      }
      wsum[t] = ws;
    }
    __syncthreads();
    int excl = carry + ((wid > 0) ? wsum[wid - 1] : 0) + (incl - v);
    if (idx < nb) p[idx] = excl;
    carry += wsum[15];
    __syncthreads();
  }
}

// step 3: add chunk offsets; emit row_start (final) and cursor copy
__global__ __launch_bounds__(1024) void scan3(
    int* __restrict__ row_start, const int* __restrict__ partials,
    int* __restrict__ cursor, int nbins, int E)
{
  int i = blockIdx.x * 1024 + threadIdx.x;
  if (i < nbins) {
    int val = row_start[i] + partials[blockIdx.x];
    row_start[i] = val;
    cursor[i] = val;
  }
  if (i == 0) row_start[nbins] = E;
}

__global__ void scatter_edges(
    const int* __restrict__ send, const int* __restrict__ recv,
    const float* __restrict__ ew, int* __restrict__ cursor,
    int2* __restrict__ csr, int E, int n)
{
  int i = blockIdx.x * blockDim.x + threadIdx.x;
  if (i < E) {
    int s = send[i];
    int key = (s >> SBITS) * n + recv[i];
    int p = atomicAdd(&cursor[key], 1);
    csr[p] = make_int2(s, __float_as_int(ew[i]));
  }
}

// ---------- fused blocked SpMM + gate accumulate --------------------------
// wave owns KNODES receivers (acc in VGPRs), sweeps sender blocks in phase.
// lane = channel; per edge: broadcast {s,w} load + 256B row gather (L2-hot).
__global__ __launch_bounds__(256) void spmm_blocked(
    const float* __restrict__ x, const int* __restrict__ row_start,
    const int2* __restrict__ csr,
    const float* __restrict__ Wg, const float* __restrict__ bgp,
    float* __restrict__ x_next, float* __restrict__ out, int n,
    int nblk, int write_next)
{
  int t = threadIdx.x;
  int lane = t & 63, wid = t >> 6;
  int wave = blockIdx.x * 4 + wid;
  int node0 = wave * KNODES;
  if (node0 >= n) return;
  float wg = Wg[lane], bgv = bgp[0];

  float acc[KNODES];
#pragma unroll
  for (int d = 0; d < KNODES; ++d) acc[d] = 0.f;

  int lidx = lane < KNODES ? lane : KNODES;  // lanes 0..16 load row bounds
  for (int blk = 0; blk < nblk; ++blk) {
    int base = blk * n + node0;
    int rs = row_start[base + lidx];
#pragma unroll
    for (int d = 0; d < KNODES; ++d) {
      int beg = __shfl(rs, d, 64);
      int end = __shfl(rs, d + 1, 64);
      for (int e = beg; e < end; ++e) {
        int2 ev = csr[e];  // wave-uniform address -> broadcast
        acc[d] += __int_as_float(ev.y) * x[(size_t)ev.x * C + lane];
      }
    }
  }

#pragma unroll
  for (int d = 0; d < KNODES; ++d) {
    int node = node0 + d;
    if (node < n) {
      float p = acc[d] * wg;
#pragma unroll
      for (int off = 32; off > 0; off >>= 1) p += __shfl_xor(p, off, 64);
      float g = 1.f / (1.f + expf(-(p + bgv)));
      size_t o = (size_t)node * C + lane;
      if (write_next) x_next[o] = acc[d];
      out[o] += g * acc[d];
    }
  }
}

// ---------------------------------------------------------------------------
extern "C" void kernel_launch(void* const* d_in, const int* in_sizes, int n_in,
                              void* d_out, int out_size, void* d_ws, size_t ws_size,
                              hipStream_t stream) {
  const float* nf   = (const float*)d_in[0];
  const float* ew   = (const float*)d_in[1];
  const float* W1   = (const float*)d_in[2];
  const float* b1   = (const float*)d_in[3];
  const float* W2   = (const float*)d_in[4];
  const float* b2   = (const float*)d_in[5];
  const float* Wg   = (const float*)d_in[6];
  const float* bg   = (const float*)d_in[7];
  const int* send   = (const int*)d_in[8];
  const int* recv   = (const int*)d_in[9];
  float* out = (float*)d_out;

  int n = in_sizes[0] / F_IN;     // 100000
  int E = in_sizes[1];            // 3200000
  int nblk = (n + (1 << SBITS) - 1) >> SBITS;   // 13
  int nbins = nblk * n;                          // 1.3M
  int nchunk = (nbins + 1023) / 1024;            // scan chunks

  // workspace layout
  float* buf0 = (float*)d_ws;                       // n*64: logits / x even
  float* buf1 = buf0 + (size_t)n * C;               // n*64: h, then x odd
  int2*  csr  = (int2*)(buf1 + (size_t)n * C);      // E  {sender, weight}
  int*   row_start = (int*)(csr + E);               // nbins+1
  int*   cursor = row_start + (nbins + 1);          // nbins (hist + scatter)
  int*   partials = cursor + nbins;                 // nchunk

  // 1) h = relu(nf@W1+b1)  -> buf1
  gemm1_relu<<<(n + 63) / 64, 256, 0, stream>>>(nf, W1, b1, buf1, n);

  // 2) logits = h@W2+b2 -> buf0 ; out = sig(logits.Wg+bg)*logits
  gemm2_gate<<<(n + 3) / 4, 256, 0, stream>>>(buf1, W2, b2, Wg, bg, buf0, out, n);

  // 3) sender-blocked receiver-CSR
  hipMemsetAsync(cursor, 0, (size_t)nbins * sizeof(int), stream);
  hist_edges<<<(E + 255) / 256, 256, 0, stream>>>(send, recv, cursor, E, n);
  scan1<<<nchunk, 1024, 0, stream>>>(cursor, row_start, partials, nbins);
  scan2<<<1, 1024, 0, stream>>>(partials, nchunk);
  scan3<<<nchunk, 1024, 0, stream>>>(row_start, partials, cursor, nbins, E);
  scatter_edges<<<(E + 255) / 256, 256, 0, stream>>>(send, recv, ew, cursor,
                                                     csr, E, n);

  // 4) 20 propagation hops, gate-fused. x ping-pongs buf0 <-> buf1.
  int nwave = (n + KNODES - 1) / KNODES;
  int nblkgrid = (nwave + 3) / 4;
  float* xin = buf0;
  float* xout = buf1;
  for (int k = 0; k < 20; ++k) {
    spmm_blocked<<<nblkgrid, 256, 0, stream>>>(xin, row_start, csr,
                                               Wg, bg, xout, out, n,
                                               nblk, k < 19 ? 1 : 0);
    float* tmp = xin; xin = xout; xout = tmp;
  }
}